// Round 9
// baseline (129.836 us; speedup 1.0000x reference)
//
#include <hip/hip_runtime.h>
#include <stdint.h>

typedef _Float16 f16;
typedef _Float16 f16x4 __attribute__((ext_vector_type(4)));
typedef _Float16 f16x8 __attribute__((ext_vector_type(8)));
typedef float f32x4 __attribute__((ext_vector_type(4)));
typedef float f32x16 __attribute__((ext_vector_type(16)));

typedef const __attribute__((address_space(1))) void* gas_ptr;
typedef __attribute__((address_space(3))) void* las_ptr;

__device__ __forceinline__ void gload16(const void* g, void* l) {
  __builtin_amdgcn_global_load_lds((gas_ptr)g, (las_ptr)l, 16, 0, 0);
}

// ws layout (bytes)
#define OFF_A16 0u              // [8192][2048] f16  (x1_att rows 0..4095, x2_att rows 4096..8191)
#define OFF_W16 33554432u       // [1024][2048] f16
#define OFF_K16 37748736u       // keys [8192][1024] f16
#define OFF_VT  54525952u       // V^T  [8][8][128][512] f16
#define WS_NEED 62914560u

// ---------------- kernel 1: f32 -> f16 convert (A and W), grid-stride ----------------
__global__ void k_convert(const float* __restrict__ x1a, const float* __restrict__ x2a,
                          const float* __restrict__ W, f16* __restrict__ A16,
                          f16* __restrict__ W16) {
  const int NA = (8192 * 2048) / 4;  // 4194304 groups of 4
  const int NH = NA / 2;
  const int NW = (1024 * 2048) / 4;  // 524288
  const int NT = NA + NW;
  for (int g = blockIdx.x * blockDim.x + threadIdx.x; g < NT; g += gridDim.x * blockDim.x) {
    if (g < NA) {
      const float* src = (g < NH) ? (x1a + 4 * (size_t)g) : (x2a + 4 * (size_t)(g - NH));
      float4 v = *(const float4*)src;
      f16x4 h; h[0] = (f16)v.x; h[1] = (f16)v.y; h[2] = (f16)v.z; h[3] = (f16)v.w;
      *((f16x4*)A16 + g) = h;
    } else {
      int gw = g - NA;
      float4 v = *((const float4*)W + gw);
      f16x4 h; h[0] = (f16)v.x; h[1] = (f16)v.y; h[2] = (f16)v.z; h[3] = (f16)v.w;
      *((f16x4*)W16 + gw) = h;
    }
  }
}

// ---------------- kernel 2: build V^T per level ----------------
// VT[((b*8+n)*128 + d)*512 + k] = (f16) x2[(b*512+k)*1024 + n*128 + d]
__global__ void k_transpose_v(const float* __restrict__ x2, f16* __restrict__ VT) {
  __shared__ f16 T[128 * 130];  // [d][k] padded (stride 130 -> bank step 65 = odd)
  int bid = blockIdx.x;
  int kt = bid & 3, n = (bid >> 2) & 7, b = bid >> 5;
  int t = threadIdx.x;
  int k0 = kt * 128;
  #pragma unroll
  for (int p = 0; p < 16; ++p) {
    int kl = p * 8 + (t >> 5);
    int c4 = t & 31;
    float4 v = *(const float4*)(x2 + (size_t)(b * 512 + k0 + kl) * 1024 + n * 128 + c4 * 4);
    int d0 = c4 * 4;
    T[(d0 + 0) * 130 + kl] = (f16)v.x;
    T[(d0 + 1) * 130 + kl] = (f16)v.y;
    T[(d0 + 2) * 130 + kl] = (f16)v.z;
    T[(d0 + 3) * 130 + kl] = (f16)v.w;
  }
  __syncthreads();
  #pragma unroll
  for (int p = 0; p < 8; ++p) {
    int d = p * 16 + (t >> 4);
    int c = t & 15;
    f16x8 h;
    #pragma unroll
    for (int j = 0; j < 8; ++j) h[j] = T[d * 130 + c * 8 + j];
    *(f16x8*)(VT + (size_t)((b * 8 + n) * 128 + d) * 512 + k0 + c * 8) = h;
  }
}

// ---------------- kernel 3: keys = relu(A @ W^T) [*final_v for x2 rows] ----------------
// 128x128 tile, BK=64, 4 waves (2x2), each wave 64x64 via 2x2 32x32x16 frags.
// FRAGMENT-LINEAR LDS: unit u=(h*8+mi*4+ks2)*64+lane holds A[h*64+mi*32+(lane&31)]
// [kslot=ks2*2+(lane>>5)]. Reads are lane-linear (conflict-free); the permutation
// lives in the precomputed global source addresses (rule #21 both-sides).
__global__ void __launch_bounds__(256)
k_gemm_keys(const f16* __restrict__ A16, const f16* __restrict__ W16,
            const float* __restrict__ final_v, f16* __restrict__ K16) {
  __shared__ f16 Alds[128 * 64];
  __shared__ f16 Wlds[128 * 64];
  int bid = blockIdx.x;
  int sw = (bid & 7) * 64 + (bid >> 3);  // XCD swizzle (512 % 8 == 0, bijective)
  int mt = sw >> 3, nt = sw & 7;
  int t = threadIdx.x, l = t & 63, w = t >> 6;
  int wm = w >> 1, wn = w & 1;
  f32x16 acc[2][2];
  #pragma unroll
  for (int i = 0; i < 2; ++i)
    #pragma unroll
    for (int j = 0; j < 2; ++j)
      #pragma unroll
      for (int r = 0; r < 16; ++r) acc[i][j][r] = 0.f;
  const char* Ab = (const char*)A16 + (size_t)mt * 128 * 4096;
  const char* Wb = (const char*)W16 + (size_t)nt * 128 * 4096;
  // stage source pointers: instruction s=w*4+i stages units s*64..s*64+63
  const char* srcA[4];
  const char* srcW[4];
  #pragma unroll
  for (int i = 0; i < 4; ++i) {
    int s = w * 4 + i;
    int row = (s >> 3) * 64 + ((s >> 2) & 1) * 32 + (l & 31);
    int koff = ((s & 3) * 2 + (l >> 5)) * 16;
    srcA[i] = Ab + (size_t)row * 4096 + koff;
    srcW[i] = Wb + (size_t)row * 4096 + koff;
  }
  char* ldsA_w = (char*)Alds + w * 4096;
  char* ldsW_w = (char*)Wlds + w * 4096;
  const char* rdA = (const char*)Alds + (wm * 8) * 1024 + l * 16;
  const char* rdB = (const char*)Wlds + (wn * 8) * 1024 + l * 16;
  for (int ks = 0; ks < 32; ++ks) {
    int k0b = ks * 128;  // 64 f16 = 128 bytes per step
    #pragma unroll
    for (int i = 0; i < 4; ++i) {
      gload16(srcA[i] + k0b, ldsA_w + i * 1024);
      gload16(srcW[i] + k0b, ldsW_w + i * 1024);
    }
    __syncthreads();
    f16x8 af[2][4], bf[2][4];
    #pragma unroll
    for (int mi = 0; mi < 2; ++mi)
      #pragma unroll
      for (int ks2 = 0; ks2 < 4; ++ks2) {
        af[mi][ks2] = *(const f16x8*)(rdA + (mi * 4 + ks2) * 1024);
        bf[mi][ks2] = *(const f16x8*)(rdB + (mi * 4 + ks2) * 1024);
      }
    #pragma unroll
    for (int ks2 = 0; ks2 < 4; ++ks2)
      #pragma unroll
      for (int mi = 0; mi < 2; ++mi)
        #pragma unroll
        for (int ni = 0; ni < 2; ++ni)
          acc[mi][ni] = __builtin_amdgcn_mfma_f32_32x32x16_f16(af[mi][ks2], bf[ni][ks2], acc[mi][ni], 0, 0, 0);
    __syncthreads();
  }
  // epilogue: C/D layout col=lane&31, row=(reg&3)+8*(reg>>2)+4*(lane>>5)
  bool isx2 = (mt >= 32);
  int c = l & 31, r2 = l >> 5;
  #pragma unroll
  for (int ni = 0; ni < 2; ++ni) {
    int col = nt * 128 + wn * 64 + ni * 32 + c;
    float fvv = isx2 ? final_v[col] : 1.0f;
    #pragma unroll
    for (int mi = 0; mi < 2; ++mi) {
      int rowbase = mt * 128 + wm * 64 + mi * 32 + 4 * r2;
      #pragma unroll
      for (int r = 0; r < 16; ++r) {
        int row = rowbase + (r & 3) + 8 * (r >> 2);
        K16[(size_t)row * 1024 + col] = (f16)(fmaxf(acc[mi][ni][r], 0.f) * fvv);
      }
    }
  }
}

// ---------------- kernel 4: flash attention per (b, level, 64-row q tile) ----------------
__global__ void __launch_bounds__(256)
k_attn(const f16* __restrict__ K16, const f16* __restrict__ VT,
       const int* __restrict__ mask, float* __restrict__ out) {
  __shared__ f16 Qlds[64 * 128];
  __shared__ f16 Klds[64 * 128];
  __shared__ f16 Vlds[128 * 64];
  __shared__ f16 Plds[4 * 16 * 64];
  __shared__ float bias[512];
  int bid = blockIdx.x;
  int qt = bid & 7, n = (bid >> 3) & 7, b = bid >> 6;
  int t = threadIdx.x, l = t & 63, w = t >> 6;
  for (int i = t; i < 512; i += 256) bias[i] = mask[b * 512 + i] ? -1e30f : 0.0f;
  int r4 = l >> 4;
  int slot = (l & 15) << 4;
  int lg = r4 << 4;
  const char* Qg = (const char*)K16 + ((size_t)(b * 512 + qt * 64) * 1024 + n * 128) * 2;
  #pragma unroll
  for (int i = 0; i < 4; ++i) {
    int rl = w * 16 + i * 4 + r4;
    gload16(Qg + (size_t)rl * 2048 + (slot ^ ((rl & 7) << 4)),
            (char*)Qlds + (w * 16 + i * 4) * 256);
  }
  __syncthreads();
  int qrow = w * 16 + (l & 15);
  int qsz = (qrow & 7) << 4;
  f16x8 qf[4];
  #pragma unroll
  for (int kk = 0; kk < 4; ++kk)
    qf[kk] = *(const f16x8*)((const char*)Qlds + qrow * 256 + ((kk * 64 + lg) ^ qsz));
  f32x4 o[8];
  #pragma unroll
  for (int dt = 0; dt < 8; ++dt) { o[dt][0] = 0.f; o[dt][1] = 0.f; o[dt][2] = 0.f; o[dt][3] = 0.f; }
  float m_r[4], l_r[4];
  #pragma unroll
  for (int r = 0; r < 4; ++r) { m_r[r] = -1e30f; l_r[r] = 0.0f; }
  const char* Kg = (const char*)K16 + ((size_t)(4096 + b * 512) * 1024 + n * 128) * 2;
  const char* Vg = (const char*)VT + (size_t)((b * 8 + n) * 128) * 1024;
  int vr = l >> 3;
  int vslot = (l & 7) << 4;
  char* Pw = (char*)Plds + w * 2048;
  for (int kt = 0; kt < 8; ++kt) {
    #pragma unroll
    for (int i = 0; i < 4; ++i) {
      int rl = w * 16 + i * 4 + r4;
      gload16(Kg + (size_t)(kt * 64 + rl) * 2048 + (slot ^ ((rl & 7) << 4)),
              (char*)Klds + (w * 16 + i * 4) * 256);
    }
    #pragma unroll
    for (int i = 0; i < 4; ++i) {
      int dl = w * 32 + i * 8 + vr;
      gload16(Vg + (size_t)dl * 1024 + kt * 128 + (vslot ^ ((dl & 7) << 4)),
              (char*)Vlds + (w * 32 + i * 8) * 128);
    }
    __syncthreads();
    f32x4 s[4];
    #pragma unroll
    for (int nt4 = 0; nt4 < 4; ++nt4) {
      s[nt4][0] = 0.f; s[nt4][1] = 0.f; s[nt4][2] = 0.f; s[nt4][3] = 0.f;
      int krow = nt4 * 16 + (l & 15);
      int ksz = (krow & 7) << 4;
      #pragma unroll
      for (int kk = 0; kk < 4; ++kk) {
        f16x8 kf = *(const f16x8*)((const char*)Klds + krow * 256 + ((kk * 64 + lg) ^ ksz));
        s[nt4] = __builtin_amdgcn_mfma_f32_16x16x32_f16(qf[kk], kf, s[nt4], 0, 0, 0);
      }
      float bc = bias[kt * 64 + nt4 * 16 + (l & 15)];
      #pragma unroll
      for (int r = 0; r < 4; ++r) s[nt4][r] += bc;
    }
    float pmax[4], scale[4], csum[4];
    #pragma unroll
    for (int r = 0; r < 4; ++r)
      pmax[r] = fmaxf(fmaxf(s[0][r], s[1][r]), fmaxf(s[2][r], s[3][r]));
    #pragma unroll
    for (int off = 1; off <= 8; off <<= 1) {
      #pragma unroll
      for (int r = 0; r < 4; ++r) pmax[r] = fmaxf(pmax[r], __shfl_xor(pmax[r], off));
    }
    #pragma unroll
    for (int r = 0; r < 4; ++r) {
      float mn = fmaxf(m_r[r], pmax[r]);
      scale[r] = __expf(m_r[r] - mn);
      m_r[r] = mn;
      csum[r] = 0.0f;
    }
    #pragma unroll
    for (int nt4 = 0; nt4 < 4; ++nt4) {
      #pragma unroll
      for (int r = 0; r < 4; ++r) {
        float sv = s[nt4][r];
        float p = (sv <= -1e29f) ? 0.0f : __expf(sv - m_r[r]);
        csum[r] += p;
        int prow = (r4 << 2) + r;
        int addr = prow * 128 + (((nt4 * 16 + (l & 15)) * 2) ^ ((prow & 7) << 4));
        *(f16*)(Pw + addr) = (f16)p;
      }
    }
    #pragma unroll
    for (int off = 1; off <= 8; off <<= 1) {
      #pragma unroll
      for (int r = 0; r < 4; ++r) csum[r] += __shfl_xor(csum[r], off);
    }
    #pragma unroll
    for (int r = 0; r < 4; ++r) l_r[r] = l_r[r] * scale[r] + csum[r];
    #pragma unroll
    for (int dt = 0; dt < 8; ++dt) {
      #pragma unroll
      for (int r = 0; r < 4; ++r) o[dt][r] *= scale[r];
    }
    asm volatile("s_waitcnt lgkmcnt(0)" ::: "memory");  // P writes visible to own-wave reads
    int prow = l & 15;
    int psz = (prow & 7) << 4;
    f16x8 pf0 = *(const f16x8*)((const char*)Pw + prow * 128 + (lg ^ psz));
    f16x8 pf1 = *(const f16x8*)((const char*)Pw + prow * 128 + ((lg + 64) ^ psz));
    #pragma unroll
    for (int dt = 0; dt < 8; ++dt) {
      int drow = dt * 16 + (l & 15);
      int dsz = (drow & 7) << 4;
      f16x8 vf0 = *(const f16x8*)((const char*)Vlds + drow * 128 + (lg ^ dsz));
      f16x8 vf1 = *(const f16x8*)((const char*)Vlds + drow * 128 + ((lg + 64) ^ dsz));
      o[dt] = __builtin_amdgcn_mfma_f32_16x16x32_f16(pf0, vf0, o[dt], 0, 0, 0);
      o[dt] = __builtin_amdgcn_mfma_f32_16x16x32_f16(pf1, vf1, o[dt], 0, 0, 0);
    }
    __syncthreads();
  }
  size_t ob = (size_t)(b * 512 + qt * 64 + w * 16 + (r4 << 2)) * 1024 + n * 128 + (l & 15);
  #pragma unroll
  for (int r = 0; r < 4; ++r) {
    float inv = 1.0f / fmaxf(l_r[r], 1e-30f);
    #pragma unroll
    for (int dt = 0; dt < 8; ++dt)
      out[ob + (size_t)r * 1024 + dt * 16] = o[dt][r] * inv;
  }
}

extern "C" void kernel_launch(void* const* d_in, const int* in_sizes, int n_in,
                              void* d_out, int out_size, void* d_ws, size_t ws_size,
                              hipStream_t stream) {
  const float* x1a = (const float*)d_in[0];
  const float* x2a = (const float*)d_in[1];
  const float* x2  = (const float*)d_in[2];
  const int*   msk = (const int*)d_in[3];
  const float* W   = (const float*)d_in[4];
  const float* fv  = (const float*)d_in[5];
  float* out = (float*)d_out;
  if (ws_size < (size_t)WS_NEED) return;  // ws too small: fail loudly via unmodified (poisoned) d_out
  char* ws = (char*)d_ws;
  f16* A16 = (f16*)(ws + OFF_A16);
  f16* W16 = (f16*)(ws + OFF_W16);
  f16* K16 = (f16*)(ws + OFF_K16);
  f16* VT  = (f16*)(ws + OFF_VT);
  k_convert<<<2048, 256, 0, stream>>>(x1a, x2a, W, A16, W16);
  k_transpose_v<<<256, 256, 0, stream>>>(x2, VT);
  k_gemm_keys<<<512, 256, 0, stream>>>(A16, W16, fv, K16);
  k_attn<<<512, 256, 0, stream>>>(K16, VT, msk, out);
}

// Round 10
// 96.401 us; speedup vs baseline: 1.3468x; 1.3468x over previous
//
#include <hip/hip_runtime.h>
#include <stdint.h>

typedef _Float16 f16;
typedef _Float16 f16x4 __attribute__((ext_vector_type(4)));
typedef _Float16 f16x8 __attribute__((ext_vector_type(8)));
typedef float f32x4 __attribute__((ext_vector_type(4)));
typedef float f32x16 __attribute__((ext_vector_type(16)));

typedef const __attribute__((address_space(1))) void* gas_ptr;
typedef __attribute__((address_space(3))) void* las_ptr;

__device__ __forceinline__ void gload16(const void* g, void* l) {
  __builtin_amdgcn_global_load_lds((gas_ptr)g, (las_ptr)l, 16, 0, 0);
}

// ws layout (bytes)
#define OFF_A16 0u              // [8192][2048] f16  (x1_att rows 0..4095, x2_att rows 4096..8191)
#define OFF_W16 33554432u       // [1024][2048] f16
#define OFF_K16 37748736u       // keys [8192][1024] f16
#define OFF_VT  54525952u       // V^T  [8][8][128][512] f16
#define WS_NEED 62914560u

// ---------------- kernel 1: f32 -> f16 convert (A and W), grid-stride ----------------
__global__ void k_convert(const float* __restrict__ x1a, const float* __restrict__ x2a,
                          const float* __restrict__ W, f16* __restrict__ A16,
                          f16* __restrict__ W16) {
  const int NA = (8192 * 2048) / 4;  // 4194304 groups of 4
  const int NH = NA / 2;
  const int NW = (1024 * 2048) / 4;  // 524288
  const int NT = NA + NW;
  for (int g = blockIdx.x * blockDim.x + threadIdx.x; g < NT; g += gridDim.x * blockDim.x) {
    if (g < NA) {
      const float* src = (g < NH) ? (x1a + 4 * (size_t)g) : (x2a + 4 * (size_t)(g - NH));
      float4 v = *(const float4*)src;
      f16x4 h; h[0] = (f16)v.x; h[1] = (f16)v.y; h[2] = (f16)v.z; h[3] = (f16)v.w;
      *((f16x4*)A16 + g) = h;
    } else {
      int gw = g - NA;
      float4 v = *((const float4*)W + gw);
      f16x4 h; h[0] = (f16)v.x; h[1] = (f16)v.y; h[2] = (f16)v.z; h[3] = (f16)v.w;
      *((f16x4*)W16 + gw) = h;
    }
  }
}

// ---------------- kernel 2: build V^T per level ----------------
// VT[((b*8+n)*128 + d)*512 + k] = (f16) x2[(b*512+k)*1024 + n*128 + d]
__global__ void k_transpose_v(const float* __restrict__ x2, f16* __restrict__ VT) {
  __shared__ f16 T[128 * 130];  // [d][k] padded (stride 130 -> bank step 65 = odd)
  int bid = blockIdx.x;
  int kt = bid & 3, n = (bid >> 2) & 7, b = bid >> 5;
  int t = threadIdx.x;
  int k0 = kt * 128;
  #pragma unroll
  for (int p = 0; p < 16; ++p) {
    int kl = p * 8 + (t >> 5);
    int c4 = t & 31;
    float4 v = *(const float4*)(x2 + (size_t)(b * 512 + k0 + kl) * 1024 + n * 128 + c4 * 4);
    int d0 = c4 * 4;
    T[(d0 + 0) * 130 + kl] = (f16)v.x;
    T[(d0 + 1) * 130 + kl] = (f16)v.y;
    T[(d0 + 2) * 130 + kl] = (f16)v.z;
    T[(d0 + 3) * 130 + kl] = (f16)v.w;
  }
  __syncthreads();
  #pragma unroll
  for (int p = 0; p < 8; ++p) {
    int d = p * 16 + (t >> 4);
    int c = t & 15;
    f16x8 h;
    #pragma unroll
    for (int j = 0; j < 8; ++j) h[j] = T[d * 130 + c * 8 + j];
    *(f16x8*)(VT + (size_t)((b * 8 + n) * 128 + d) * 512 + k0 + c * 8) = h;
  }
}

// ---------------- kernel 3: keys = relu(A @ W^T) [*final_v for x2 rows] ----------------
// 128x128 tile, BK=128 (16 K-steps: half the barrier/drain events of BK=64; we are
// grid-limited at 2 blocks/CU so m132's occupancy cost doesn't apply).
// Tile rows are 256B = 16 x 16B slots; swizzle slot' = slot ^ (row&15); stage
// instruction covers 4 rows x 256B contiguous global (coalesced), permutation
// stays WITHIN each row (R9 lesson: never permute across rows in the source).
__global__ void __launch_bounds__(256)
k_gemm_keys(const f16* __restrict__ A16, const f16* __restrict__ W16,
            const float* __restrict__ final_v, f16* __restrict__ K16) {
  __shared__ f16 Alds[128 * 128];
  __shared__ f16 Wlds[128 * 128];
  int bid = blockIdx.x;
  int sw = (bid & 7) * 64 + (bid >> 3);  // XCD swizzle (512 % 8 == 0, bijective)
  int mt = sw >> 3, nt = sw & 7;
  int t = threadIdx.x, l = t & 63, w = t >> 6;
  int wm = w >> 1, wn = w & 1;
  f32x16 acc[2][2];
  #pragma unroll
  for (int i = 0; i < 2; ++i)
    #pragma unroll
    for (int j = 0; j < 2; ++j)
      #pragma unroll
      for (int r = 0; r < 16; ++r) acc[i][j][r] = 0.f;
  const char* Ab = (const char*)A16 + (size_t)mt * 128 * 4096;
  const char* Wb = (const char*)W16 + (size_t)nt * 128 * 4096;
  // stage: instruction i covers LDS units (w*8+i)*64 + l -> row=(w*8+i)*4+(l>>4),
  // slot_lds=l&15; global src = row*4096 + k0b + (slot_lds ^ (row&15))*16
  size_t soff[8];
  #pragma unroll
  for (int i = 0; i < 8; ++i) {
    int row = (w * 8 + i) * 4 + (l >> 4);
    soff[i] = (size_t)row * 4096 + (((l & 15) ^ (row & 15)) << 4);
  }
  // read bases: lane l reads row = base + (l&31), k-slot = ks2*2 + (l>>5)
  int g8 = l >> 5;
  int rowA = wm * 64 + (l & 31);
  int rowB = wn * 64 + (l & 31);
  int sA = rowA & 15, sB = rowB & 15;
  const char* rdA0 = (const char*)Alds + rowA * 256;
  const char* rdB0 = (const char*)Wlds + rowB * 256;
  for (int ks = 0; ks < 16; ++ks) {
    int k0b = ks * 256;  // 128 f16 = 256 bytes per step
    #pragma unroll
    for (int i = 0; i < 8; ++i) {
      gload16(Ab + soff[i] + k0b, (char*)Alds + (w * 8 + i) * 1024);
      gload16(Wb + soff[i] + k0b, (char*)Wlds + (w * 8 + i) * 1024);
    }
    __syncthreads();
    f16x8 af[2][8], bf[2][8];
    #pragma unroll
    for (int mi = 0; mi < 2; ++mi)
      #pragma unroll
      for (int ks2 = 0; ks2 < 8; ++ks2) {
        af[mi][ks2] = *(const f16x8*)(rdA0 + mi * 8192 + (((ks2 * 2 + g8) ^ sA) << 4));
        bf[mi][ks2] = *(const f16x8*)(rdB0 + mi * 8192 + (((ks2 * 2 + g8) ^ sB) << 4));
      }
    #pragma unroll
    for (int ks2 = 0; ks2 < 8; ++ks2)
      #pragma unroll
      for (int mi = 0; mi < 2; ++mi)
        #pragma unroll
        for (int ni = 0; ni < 2; ++ni)
          acc[mi][ni] = __builtin_amdgcn_mfma_f32_32x32x16_f16(af[mi][ks2], bf[ni][ks2], acc[mi][ni], 0, 0, 0);
    __syncthreads();
  }
  // epilogue: C/D layout col=lane&31, row=(reg&3)+8*(reg>>2)+4*(lane>>5)
  bool isx2 = (mt >= 32);
  int c = l & 31, r2 = l >> 5;
  #pragma unroll
  for (int ni = 0; ni < 2; ++ni) {
    int col = nt * 128 + wn * 64 + ni * 32 + c;
    float fvv = isx2 ? final_v[col] : 1.0f;
    #pragma unroll
    for (int mi = 0; mi < 2; ++mi) {
      int rowbase = mt * 128 + wm * 64 + mi * 32 + 4 * r2;
      #pragma unroll
      for (int r = 0; r < 16; ++r) {
        int row = rowbase + (r & 3) + 8 * (r >> 2);
        K16[(size_t)row * 1024 + col] = (f16)(fmaxf(acc[mi][ni][r], 0.f) * fvv);
      }
    }
  }
}

// ---------------- kernel 4: flash attention per (b, level, 64-row q tile) ----------------
__global__ void __launch_bounds__(256)
k_attn(const f16* __restrict__ K16, const f16* __restrict__ VT,
       const int* __restrict__ mask, float* __restrict__ out) {
  __shared__ f16 Qlds[64 * 128];
  __shared__ f16 Klds[64 * 128];
  __shared__ f16 Vlds[128 * 64];
  __shared__ f16 Plds[4 * 16 * 64];
  __shared__ float bias[512];
  int bid = blockIdx.x;
  int qt = bid & 7, n = (bid >> 3) & 7, b = bid >> 6;
  int t = threadIdx.x, l = t & 63, w = t >> 6;
  for (int i = t; i < 512; i += 256) bias[i] = mask[b * 512 + i] ? -1e30f : 0.0f;
  int r4 = l >> 4;
  int slot = (l & 15) << 4;
  int lg = r4 << 4;
  const char* Qg = (const char*)K16 + ((size_t)(b * 512 + qt * 64) * 1024 + n * 128) * 2;
  #pragma unroll
  for (int i = 0; i < 4; ++i) {
    int rl = w * 16 + i * 4 + r4;
    gload16(Qg + (size_t)rl * 2048 + (slot ^ ((rl & 7) << 4)),
            (char*)Qlds + (w * 16 + i * 4) * 256);
  }
  __syncthreads();
  int qrow = w * 16 + (l & 15);
  int qsz = (qrow & 7) << 4;
  f16x8 qf[4];
  #pragma unroll
  for (int kk = 0; kk < 4; ++kk)
    qf[kk] = *(const f16x8*)((const char*)Qlds + qrow * 256 + ((kk * 64 + lg) ^ qsz));
  f32x4 o[8];
  #pragma unroll
  for (int dt = 0; dt < 8; ++dt) { o[dt][0] = 0.f; o[dt][1] = 0.f; o[dt][2] = 0.f; o[dt][3] = 0.f; }
  float m_r[4], l_r[4];
  #pragma unroll
  for (int r = 0; r < 4; ++r) { m_r[r] = -1e30f; l_r[r] = 0.0f; }
  const char* Kg = (const char*)K16 + ((size_t)(4096 + b * 512) * 1024 + n * 128) * 2;
  const char* Vg = (const char*)VT + (size_t)((b * 8 + n) * 128) * 1024;
  int vr = l >> 3;
  int vslot = (l & 7) << 4;
  char* Pw = (char*)Plds + w * 2048;
  for (int kt = 0; kt < 8; ++kt) {
    #pragma unroll
    for (int i = 0; i < 4; ++i) {
      int rl = w * 16 + i * 4 + r4;
      gload16(Kg + (size_t)(kt * 64 + rl) * 2048 + (slot ^ ((rl & 7) << 4)),
              (char*)Klds + (w * 16 + i * 4) * 256);
    }
    #pragma unroll
    for (int i = 0; i < 4; ++i) {
      int dl = w * 32 + i * 8 + vr;
      gload16(Vg + (size_t)dl * 1024 + kt * 128 + (vslot ^ ((dl & 7) << 4)),
              (char*)Vlds + (w * 32 + i * 8) * 128);
    }
    __syncthreads();
    f32x4 s[4];
    #pragma unroll
    for (int nt4 = 0; nt4 < 4; ++nt4) {
      s[nt4][0] = 0.f; s[nt4][1] = 0.f; s[nt4][2] = 0.f; s[nt4][3] = 0.f;
      int krow = nt4 * 16 + (l & 15);
      int ksz = (krow & 7) << 4;
      #pragma unroll
      for (int kk = 0; kk < 4; ++kk) {
        f16x8 kf = *(const f16x8*)((const char*)Klds + krow * 256 + ((kk * 64 + lg) ^ ksz));
        s[nt4] = __builtin_amdgcn_mfma_f32_16x16x32_f16(qf[kk], kf, s[nt4], 0, 0, 0);
      }
      float bc = bias[kt * 64 + nt4 * 16 + (l & 15)];
      #pragma unroll
      for (int r = 0; r < 4; ++r) s[nt4][r] += bc;
    }
    float pmax[4], scale[4], csum[4];
    #pragma unroll
    for (int r = 0; r < 4; ++r)
      pmax[r] = fmaxf(fmaxf(s[0][r], s[1][r]), fmaxf(s[2][r], s[3][r]));
    #pragma unroll
    for (int off = 1; off <= 8; off <<= 1) {
      #pragma unroll
      for (int r = 0; r < 4; ++r) pmax[r] = fmaxf(pmax[r], __shfl_xor(pmax[r], off));
    }
    #pragma unroll
    for (int r = 0; r < 4; ++r) {
      float mn = fmaxf(m_r[r], pmax[r]);
      scale[r] = __expf(m_r[r] - mn);
      m_r[r] = mn;
      csum[r] = 0.0f;
    }
    #pragma unroll
    for (int nt4 = 0; nt4 < 4; ++nt4) {
      #pragma unroll
      for (int r = 0; r < 4; ++r) {
        float sv = s[nt4][r];
        float p = (sv <= -1e29f) ? 0.0f : __expf(sv - m_r[r]);
        csum[r] += p;
        int prow = (r4 << 2) + r;
        int addr = prow * 128 + (((nt4 * 16 + (l & 15)) * 2) ^ ((prow & 7) << 4));
        *(f16*)(Pw + addr) = (f16)p;
      }
    }
    #pragma unroll
    for (int off = 1; off <= 8; off <<= 1) {
      #pragma unroll
      for (int r = 0; r < 4; ++r) csum[r] += __shfl_xor(csum[r], off);
    }
    #pragma unroll
    for (int r = 0; r < 4; ++r) l_r[r] = l_r[r] * scale[r] + csum[r];
    #pragma unroll
    for (int dt = 0; dt < 8; ++dt) {
      #pragma unroll
      for (int r = 0; r < 4; ++r) o[dt][r] *= scale[r];
    }
    asm volatile("s_waitcnt lgkmcnt(0)" ::: "memory");  // P writes visible to own-wave reads
    int prow = l & 15;
    int psz = (prow & 7) << 4;
    f16x8 pf0 = *(const f16x8*)((const char*)Pw + prow * 128 + (lg ^ psz));
    f16x8 pf1 = *(const f16x8*)((const char*)Pw + prow * 128 + ((lg + 64) ^ psz));
    #pragma unroll
    for (int dt = 0; dt < 8; ++dt) {
      int drow = dt * 16 + (l & 15);
      int dsz = (drow & 7) << 4;
      f16x8 vf0 = *(const f16x8*)((const char*)Vlds + drow * 128 + (lg ^ dsz));
      f16x8 vf1 = *(const f16x8*)((const char*)Vlds + drow * 128 + ((lg + 64) ^ dsz));
      o[dt] = __builtin_amdgcn_mfma_f32_16x16x32_f16(pf0, vf0, o[dt], 0, 0, 0);
      o[dt] = __builtin_amdgcn_mfma_f32_16x16x32_f16(pf1, vf1, o[dt], 0, 0, 0);
    }
    __syncthreads();
  }
  size_t ob = (size_t)(b * 512 + qt * 64 + w * 16 + (r4 << 2)) * 1024 + n * 128 + (l & 15);
  #pragma unroll
  for (int r = 0; r < 4; ++r) {
    float inv = 1.0f / fmaxf(l_r[r], 1e-30f);
    #pragma unroll
    for (int dt = 0; dt < 8; ++dt)
      out[ob + (size_t)r * 1024 + dt * 16] = o[dt][r] * inv;
  }
}

extern "C" void kernel_launch(void* const* d_in, const int* in_sizes, int n_in,
                              void* d_out, int out_size, void* d_ws, size_t ws_size,
                              hipStream_t stream) {
  const float* x1a = (const float*)d_in[0];
  const float* x2a = (const float*)d_in[1];
  const float* x2  = (const float*)d_in[2];
  const int*   msk = (const int*)d_in[3];
  const float* W   = (const float*)d_in[4];
  const float* fv  = (const float*)d_in[5];
  float* out = (float*)d_out;
  if (ws_size < (size_t)WS_NEED) return;  // ws too small: fail loudly via unmodified (poisoned) d_out
  char* ws = (char*)d_ws;
  f16* A16 = (f16*)(ws + OFF_A16);
  f16* W16 = (f16*)(ws + OFF_W16);
  f16* K16 = (f16*)(ws + OFF_K16);
  f16* VT  = (f16*)(ws + OFF_VT);
  k_convert<<<2048, 256, 0, stream>>>(x1a, x2a, W, A16, W16);
  k_transpose_v<<<256, 256, 0, stream>>>(x2, VT);
  k_gemm_keys<<<512, 256, 0, stream>>>(A16, W16, fv, K16);
  k_attn<<<512, 256, 0, stream>>>(K16, VT, msk, out);
}